// Round 1
// 297.900 us; speedup vs baseline: 1.0021x; 1.0021x over previous
//
#include <hip/hip_runtime.h>

// GraphConvolution: out[b,i,o] = relu( sum_f AX[b,i,f] * W[o,f] + bias[o] )
// AX[b,i,:] = w_i * (x[b,i-1,:] + x[b,i,:] + x[b,i+1,:]),  w_i = 1/2 ends, 1/3 interior
//
// R3: vectorized epilogue. MFMA operands swapped vs R2: mfma(W_frag, AX_frag, acc)
// puts the output-feature dim on D's rows, so each lane's acc[j] (row=quad*4+j)
// holds 4 CONSECUTIVE output features of one (node,batch) row -> 3 float4 stores
// per lane-iter instead of 12 scalar dword stores; bias applied as float4.
// Staging phase identical to R2 (13 up-front clamped loads, strip-owned nodes).

#define NODES 55
#define F 48
#define BT 4              // batches per block
#define ROWS 224          // 56 padded nodes * BT; rows 220..223 zeroed
#define ST 56             // LDS row stride in bf16 elems (112 B): r,r+8 alias = 2-way (free)

typedef __attribute__((ext_vector_type(8))) short short8_t;
typedef __attribute__((ext_vector_type(4))) float floatx4;

__device__ __forceinline__ unsigned short f2bf(float f) {
    union { float f; unsigned int u; } v; v.f = f;
    unsigned int u = v.u;
    u += 0x7FFFu + ((u >> 16) & 1u);   // round-to-nearest-even
    return (unsigned short)(u >> 16);
}

__global__ __launch_bounds__(256, 4)
void gconv_kernel(const float* __restrict__ x, const float* __restrict__ W,
                  const float* __restrict__ bias, float* __restrict__ out) {
    __shared__ unsigned short s_ax[ROWS * ST];  // 25088 B
    __shared__ unsigned short s_w[F * ST];      //  5376 B

    const int tid = threadIdx.x;
    const int b0 = blockIdx.x * BT;

    // ---- zero tail rows 220..223 (node 55 pad), cols 0..47: threads 240..255 ----
    if (tid >= 240) {
        int i = tid - 240;
        for (int t = i; t < 48; t += 16) {           // 48 x 8B chunks
            int row = 220 + (t / 12), c = t - (t / 12) * 12;
            *(uint2*)&s_ax[row * ST + c * 4] = make_uint2(0u, 0u);
        }
    }

    // ---- stage W (48x48 fp32 -> bf16), all threads ----
    for (int i = tid; i < F * F; i += 256) {
        int o = i / 48, f = i - o * 48;
        s_w[o * ST + f] = f2bf(W[i]);
    }

    // ---- strip staging: thread = (strip s in 0..4, b_l in 0..3, fq in 0..11) ----
    if (tid < 240) {
        const int s   = tid / 48;
        const int rem = tid - s * 48;
        const int b_l = rem / 12;
        const int fq  = rem - b_l * 12;
        const float4* xg = reinterpret_cast<const float4*>(x);
        const int base = (b0 + b_l) * (NODES * 12) + fq;   // float4 index of node 0
        const int n0 = s * 11;

        // 13 independent loads, all issued before any use
        float4 v[13];
#pragma unroll
        for (int t = 0; t < 13; ++t) {
            int n = n0 - 1 + t;
            int nc = n < 0 ? 0 : (n > 54 ? 54 : n);
            float4 tmp = xg[base + nc * 12];
            bool ok = (n >= 0) & (n <= 54);
            v[t].x = ok ? tmp.x : 0.f;
            v[t].y = ok ? tmp.y : 0.f;
            v[t].z = ok ? tmp.z : 0.f;
            v[t].w = ok ? tmp.w : 0.f;
        }

#pragma unroll
        for (int t = 0; t < 11; ++t) {
            int n = n0 + t;
            float w = (n == 0 || n == 54) ? 0.5f : (1.0f / 3.0f);
            float sx = (v[t].x + v[t + 1].x + v[t + 2].x) * w;
            float sy = (v[t].y + v[t + 1].y + v[t + 2].y) * w;
            float sz = (v[t].z + v[t + 1].z + v[t + 2].z) * w;
            float sw = (v[t].w + v[t + 1].w + v[t + 2].w) * w;
            unsigned int lo = (unsigned int)f2bf(sx) | ((unsigned int)f2bf(sy) << 16);
            unsigned int hi = (unsigned int)f2bf(sz) | ((unsigned int)f2bf(sw) << 16);
            *(uint2*)&s_ax[(n * BT + b_l) * ST + fq * 4] = make_uint2(lo, hi);
        }
    }
    __syncthreads();

    // ---- MFMA phase ----
    const int lane = tid & 63;
    const int wave = tid >> 6;
    const int col  = lane & 15;    // own-index within a 16x16 tile
    const int quad = lane >> 4;    // k = quad*8 + j

    const short8_t zero8 = {0, 0, 0, 0, 0, 0, 0, 0};

    // all of W in registers: 3 o-tiles x 2 k-steps; k-step 1 valid only for quads 0,1 (k=32..47)
    short8_t wf[3][2];
#pragma unroll
    for (int nt = 0; nt < 3; ++nt) {
        wf[nt][0] = *(const short8_t*)&s_w[(nt * 16 + col) * ST + quad * 8];
        short8_t t1 = *(const short8_t*)&s_w[(nt * 16 + col) * ST + 32 + (quad & 1) * 8];
        wf[nt][1] = (quad < 2) ? t1 : zero8;
    }

    // bias as float4 per o-tile: rows o = mt*16 + quad*4 + j
    floatx4 bv[3];
#pragma unroll
    for (int mt = 0; mt < 3; ++mt)
        bv[mt] = *(const floatx4*)&bias[mt * 16 + quad * 4];

    for (int m = wave; m < 14; m += 4) {
        const int nb = m * 16 + col;   // (node*4 + b_local) row owned by this lane
        short8_t a0 = *(const short8_t*)&s_ax[nb * ST + quad * 8];
        short8_t t1 = *(const short8_t*)&s_ax[nb * ST + 32 + (quad & 1) * 8];
        short8_t a1 = (quad < 2) ? t1 : zero8;

        floatx4 acc0 = {0.f, 0.f, 0.f, 0.f};
        floatx4 acc1 = {0.f, 0.f, 0.f, 0.f};
        floatx4 acc2 = {0.f, 0.f, 0.f, 0.f};
        // operands swapped vs R2: D rows = o-dim (from wf), D cols = nb (from a).
        acc0 = __builtin_amdgcn_mfma_f32_16x16x32_bf16(wf[0][0], a0, acc0, 0, 0, 0);
        acc1 = __builtin_amdgcn_mfma_f32_16x16x32_bf16(wf[1][0], a0, acc1, 0, 0, 0);
        acc2 = __builtin_amdgcn_mfma_f32_16x16x32_bf16(wf[2][0], a0, acc2, 0, 0, 0);
        acc0 = __builtin_amdgcn_mfma_f32_16x16x32_bf16(wf[0][1], a1, acc0, 0, 0, 0);
        acc1 = __builtin_amdgcn_mfma_f32_16x16x32_bf16(wf[1][1], a1, acc1, 0, 0, 0);
        acc2 = __builtin_amdgcn_mfma_f32_16x16x32_bf16(wf[2][1], a1, acc2, 0, 0, 0);

        // epilogue: C/D layout col=lane&15 (-> nb), row=quad*4+j (-> o)  [m89-verified]
        const int node = nb >> 2;
        const int b_l  = nb & 3;
        if (node < NODES) {
            float* op = out + ((b0 + b_l) * NODES + node) * F + quad * 4;
            floatx4 v0 = acc0 + bv[0];
            floatx4 v1 = acc1 + bv[1];
            floatx4 v2 = acc2 + bv[2];
#pragma unroll
            for (int j = 0; j < 4; ++j) {
                v0[j] = v0[j] > 0.f ? v0[j] : 0.f;
                v1[j] = v1[j] > 0.f ? v1[j] : 0.f;
                v2[j] = v2[j] > 0.f ? v2[j] : 0.f;
            }
            *(floatx4*)(op)      = v0;   // o = quad*4 + j        (16B aligned)
            *(floatx4*)(op + 16) = v1;   // o = 16 + quad*4 + j
            *(floatx4*)(op + 32) = v2;   // o = 32 + quad*4 + j
        }
    }
}

extern "C" void kernel_launch(void* const* d_in, const int* in_sizes, int n_in,
                              void* d_out, int out_size, void* d_ws, size_t ws_size,
                              hipStream_t stream) {
    const float* x    = (const float*)d_in[0];
    const float* W    = (const float*)d_in[1];
    const float* bias = (const float*)d_in[2];
    float* out = (float*)d_out;
    const int BATCH = 16384;
    dim3 grid(BATCH / BT);
    dim3 block(256);
    gconv_kernel<<<grid, block, 0, stream>>>(x, W, bias, out);
}